// Round 6
// baseline (110.054 us; speedup 1.0000x reference)
//
#include <hip/hip_runtime.h>

#define DIM   4096
#define BATCH 2048
#define KNZ   40
#define ROWS  4      // rows per block; each row owned by a PAIR of waves
#define TPB   512    // 8 waves: wave w -> row rb = w>>1, half p = w&1
#define DPT   (DIM / TPB)   // 8 d's per thread in gather

typedef int i32x2 __attribute__((ext_vector_type(2)));

__device__ __forceinline__ float shflx(float v, int m) { return __shfl_xor(v, m, 64); }
__device__ __forceinline__ float shfls(float v, int s) { return __shfl(v, s, 64); }

// byte offset of the 8B row-group (4 bf16 rows) for dim index d. R2-proven swizzle.
__device__ __forceinline__ int OFF(int d) { return (d << 3) ^ ((d >> 3) & 248); }

__device__ __forceinline__ unsigned short bfp(float f) {   // f32 -> bf16 RNE
  unsigned u = __float_as_uint(f);
  u += 0x7fffu + ((u >> 16) & 1u);
  return (unsigned short)(u >> 16);
}
__device__ __forceinline__ float bfu(unsigned short h) { return __uint_as_float(((unsigned)h) << 16); }
__device__ __forceinline__ float blo(unsigned u) { return __uint_as_float(u << 16); }
__device__ __forceinline__ float bhi(unsigned u) { return __uint_as_float(u & 0xffff0000u); }

template<int CTRL>
__device__ __forceinline__ float dppf(float x) {
  int i = __float_as_int(x);
  return __int_as_float(__builtin_amdgcn_update_dpp(i, i, CTRL, 0xF, 0xF, false));
}

// R5-proven convention-proof butterfly element (lower: sum, upper: left-right).
template<int HL>
__device__ __forceinline__ float bfly1(float self, bool up) {
#if __has_builtin(__builtin_amdgcn_permlane32_swap)
  if constexpr (HL == 32) {
    i32x2 rr = __builtin_amdgcn_permlane32_swap(__float_as_int(self), __float_as_int(self), false, false);
    float s = __int_as_float(rr.x) + __int_as_float(rr.y);
    return up ? (s - 2.0f * self) : s;
  }
#endif
#if __has_builtin(__builtin_amdgcn_permlane16_swap)
  if constexpr (HL == 16) {
    i32x2 rr = __builtin_amdgcn_permlane16_swap(__float_as_int(self), __float_as_int(self), false, false);
    float s = __int_as_float(rr.x) + __int_as_float(rr.y);
    return up ? (s - 2.0f * self) : s;
  }
#endif
  float pv;
  if constexpr (HL == 8)      pv = dppf<0x128>(self);  // row_ror:8 == lane^8
  else if constexpr (HL == 2) pv = dppf<0x4E>(self);   // quad_perm == lane^2
  else if constexpr (HL == 1) pv = dppf<0xB1>(self);   // quad_perm == lane^1
  else                        pv = shflx(self, HL);    // HL==4 (+ fallbacks)
  float s = self + pv;
  float d = up ? (pv - self) : (self - pv);
  return up ? d : s;
}

// In-lane stage for h <= 16 on the 32-elem chunk.
template<int H>
__device__ __forceinline__ void stage_inlane(float v[32]) {
#pragma unroll
  for (int o = 0; o < 32; o += 2 * H) {
    float dt[H];
#pragma unroll
    for (int i = 0; i < H; ++i) {
      float a = v[o + i], b = v[o + H + i];
      dt[i] = a - b;
      v[o + i] = a + b;
    }
#pragma unroll
    for (int i = H - 1; i >= 1; --i) v[o + H + i] = dt[i] + dt[i - 1];
    v[o + H] = dt[0] + dt[H - 1];
  }
}

// Cross-lane stage, h = HL*32 (HL = 32..1), chunk = 32 elems/lane.
template<int HL>
__device__ __forceinline__ void stage_xlane(float v[32], int lane) {
  const bool up = (lane & HL) != 0;
  const int srcl = ((lane & (HL - 1)) == 0) ? (lane | (HL - 1)) : (lane - 1);
#pragma unroll
  for (int r = 0; r < 32; ++r) v[r] = bfly1<HL>(v[r], up);
  float dw = shfls(v[31], srcl);   // neighbor diff[31] for the r==0 roll
#pragma unroll
  for (int r = 31; r >= 1; --r) {
    float d2 = v[r] + v[r - 1];
    v[r] = up ? d2 : v[r];
  }
  float d2 = v[0] + dw;
  v[0] = up ? d2 : v[0];
}

// h=2048 stage: partner lives in the other wave of the pair. Exchange via f32
// LDS scratch in 2 chunks of 16 (scr = 2048 f32 per row). Wave p=0 holds the
// left half (keeps sum); wave p=1 holds the right half (diff = left - right,
// then roll over the whole 2048-block: borrow lane-1's last elem, wrap to 63).
__device__ __forceinline__ void stage_pair(float v[32], int lane, int p, float* scr) {
#pragma unroll
  for (int c = 0; c < 2; ++c) {
    float4* dst = (float4*)(scr + p * 1024 + lane * 16);
#pragma unroll
    for (int q = 0; q < 4; ++q)
      dst[q] = make_float4(v[16 * c + 4 * q], v[16 * c + 4 * q + 1],
                           v[16 * c + 4 * q + 2], v[16 * c + 4 * q + 3]);
    __syncthreads();
    const float4* sp = (const float4*)(scr + (p ^ 1) * 1024 + lane * 16);
    float4 q0 = sp[0], q1 = sp[1], q2 = sp[2], q3 = sp[3];
    float pv[16] = {q0.x, q0.y, q0.z, q0.w, q1.x, q1.y, q1.z, q1.w,
                    q2.x, q2.y, q2.z, q2.w, q3.x, q3.y, q3.z, q3.w};
    if (p) {
#pragma unroll
      for (int j = 0; j < 16; ++j) v[16 * c + j] = pv[j] - v[16 * c + j];
    } else {
#pragma unroll
      for (int j = 0; j < 16; ++j) v[16 * c + j] = v[16 * c + j] + pv[j];
    }
    __syncthreads();   // before chunk 2 (or next user) reuses scr
  }
  if (p) {             // roll (wave-uniform branch)
    const int srcl = (lane == 0) ? 63 : lane - 1;
    float dw = shfls(v[31], srcl);
#pragma unroll
    for (int r = 31; r >= 1; --r) v[r] = v[r] + v[r - 1];
    v[0] = v[0] + dw;
  }
}

__device__ __forceinline__ void fhh32(float v[32], int lane, int p, float* scr) {
  stage_pair(v, lane, p, scr);  // h=2048
  stage_xlane<32>(v, lane);     // h=1024
  stage_xlane<16>(v, lane);     // h=512
  stage_xlane<8>(v, lane);      // h=256
  stage_xlane<4>(v, lane);      // h=128
  stage_xlane<2>(v, lane);      // h=64
  stage_xlane<1>(v, lane);      // h=32
  stage_inlane<16>(v);          // h=16
  stage_inlane<8>(v);
  stage_inlane<4>(v);
  stage_inlane<2>(v);
  stage_inlane<1>(v);           // h=1
}

__global__ __launch_bounds__(TPB, 4) void aleph_fused(
    const float* __restrict__ x, const float* __restrict__ sw,
    const float* __restrict__ V, const int* __restrict__ I,
    float* __restrict__ out) {
  __shared__ float scratch[ROWS * 2048];         // 32 KB pair-exchange
  __shared__ unsigned short img[DIM * ROWS];     // 32 KB bf16 image (d,row)
  char* lb = (char*)img;
  const int t = threadIdx.x;
  const int w = t >> 6;
  const int lane = t & 63;
  const int rb = w >> 1;        // row within block
  const int p = w & 1;          // half of the row
  const size_t row = (size_t)blockIdx.x * ROWS + rb;
  float* scr = scratch + rb * 2048;
  const int dbase = p * 2048 + lane * 32;   // first d of this lane's chunk

  float v[32];
  {
    const float4* xp = (const float4*)(x + row * DIM + dbase);
#pragma unroll
    for (int i = 0; i < 8; ++i) {
      float4 f = xp[i];
      v[4 * i] = f.x; v[4 * i + 1] = f.y; v[4 * i + 2] = f.z; v[4 * i + 3] = f.w;
    }
  }
  fhh32(v, lane, p, scr);   // wave = transform of its half-row chunk

#pragma unroll
  for (int r = 0; r < 32; ++r)
    *(unsigned short*)(lb + OFF(dbase + r) + 2 * rb) = bfp(v[r]);
  __syncthreads();

  // Gather: thread t owns d = ii*512 + t; one ds_read_b64 yields all 4 rows.
  float preg[DPT][ROWS];
#pragma unroll
  for (int ii = 0; ii < DPT; ++ii) {
    const int d = ii * TPB + t;
    const float swd = sw[d];
    uint2 q = *(const uint2*)(lb + OFF(d));
    float a0 = blo(q.x) * swd, a1 = bhi(q.x) * swd;
    float a2 = blo(q.y) * swd, a3 = bhi(q.y) * swd;
    const int4*   ip = (const int4*)(I + d * KNZ);
    const float4* vp = (const float4*)(V + d * KNZ);
#pragma unroll 5
    for (int g = 0; g < KNZ / 4; ++g) {
      int4 i4 = ip[g];
      float4 f4 = vp[g];
      {
        uint2 qa = *(const uint2*)(lb + OFF(i4.x));
        a0 += blo(qa.x) * f4.x; a1 += bhi(qa.x) * f4.x;
        a2 += blo(qa.y) * f4.x; a3 += bhi(qa.y) * f4.x;
      }
      {
        uint2 qa = *(const uint2*)(lb + OFF(i4.y));
        a0 += blo(qa.x) * f4.y; a1 += bhi(qa.x) * f4.y;
        a2 += blo(qa.y) * f4.y; a3 += bhi(qa.y) * f4.y;
      }
      {
        uint2 qa = *(const uint2*)(lb + OFF(i4.z));
        a0 += blo(qa.x) * f4.z; a1 += bhi(qa.x) * f4.z;
        a2 += blo(qa.y) * f4.z; a3 += bhi(qa.y) * f4.z;
      }
      {
        uint2 qa = *(const uint2*)(lb + OFF(i4.w));
        a0 += blo(qa.x) * f4.w; a1 += bhi(qa.x) * f4.w;
        a2 += blo(qa.y) * f4.w; a3 += bhi(qa.y) * f4.w;
      }
    }
    preg[ii][0] = a0; preg[ii][1] = a1; preg[ii][2] = a2; preg[ii][3] = a3;
  }
  __syncthreads();   // all gathers done before in-place overwrite

#pragma unroll
  for (int ii = 0; ii < DPT; ++ii) {
    const int d = ii * TPB + t;
    ushort4 pk;
    pk.x = bfp(preg[ii][0]); pk.y = bfp(preg[ii][1]);
    pk.z = bfp(preg[ii][2]); pk.w = bfp(preg[ii][3]);
    *(ushort4*)(lb + OFF(d)) = pk;
  }
  __syncthreads();

#pragma unroll
  for (int r = 0; r < 32; ++r)
    v[r] = bfu(*(const unsigned short*)(lb + OFF(dbase + r) + 2 * rb));
  fhh32(v, lane, p, scr);   // img dead after reload; scratch reuse is safe

  const float inv = 1.0f / (float)DIM;
  float4* op = (float4*)(out + row * DIM + dbase);
#pragma unroll
  for (int i = 0; i < 8; ++i) {
    float4 f;
    f.x = v[4 * i] * inv;     f.y = v[4 * i + 1] * inv;
    f.z = v[4 * i + 2] * inv; f.w = v[4 * i + 3] * inv;
    op[i] = f;
  }
}

extern "C" void kernel_launch(void* const* d_in, const int* in_sizes, int n_in,
                              void* d_out, int out_size, void* d_ws, size_t ws_size,
                              hipStream_t stream) {
  const float* x  = (const float*)d_in[0];   // (2048, 4096) f32
  const float* sw = (const float*)d_in[1];   // (4096,) f32
  const float* V  = (const float*)d_in[2];   // (4096, 40) f32
  const int*   I  = (const int*)d_in[3];     // (4096, 40) i32
  float* out = (float*)d_out;                // (2048, 4096) f32

  dim3 grid(BATCH / ROWS), block(TPB);       // 512 blocks -> 2 per CU
  hipLaunchKernelGGL(aleph_fused, grid, block, 0, stream, x, sw, V, I, out);
}

// Round 7
// 79.406 us; speedup vs baseline: 1.3860x; 1.3860x over previous
//
#include <hip/hip_runtime.h>

#define DIM   4096
#define BATCH 2048
#define KNZ   40
#define ROWS  8      // rows per block; each row owned by a PAIR of waves
#define TPB   1024   // 16 waves: wave w -> row rb = w>>1, half p = w&1
#define DPT   (DIM / TPB)   // 4 d's per thread in gather

typedef int i32x2 __attribute__((ext_vector_type(2)));

__device__ __forceinline__ float shflx(float v, int m) { return __shfl_xor(v, m, 64); }
__device__ __forceinline__ float shfls(float v, int s) { return __shfl(v, s, 64); }

// byte offset of the 16B row-group (8 bf16 rows) for dim index d. R4-proven.
__device__ __forceinline__ int swz8(int d) { return (d << 4) ^ ((d >> 2) & 0x1f0); }

__device__ __forceinline__ unsigned short bfp(float f) {   // f32 -> bf16 RNE
  unsigned u = __float_as_uint(f);
  u += 0x7fffu + ((u >> 16) & 1u);
  return (unsigned short)(u >> 16);
}
__device__ __forceinline__ float bfu(unsigned short h) { return __uint_as_float(((unsigned)h) << 16); }
__device__ __forceinline__ float blo(unsigned u) { return __uint_as_float(u << 16); }
__device__ __forceinline__ float bhi(unsigned u) { return __uint_as_float(u & 0xffff0000u); }

template<int CTRL>
__device__ __forceinline__ float dppf(float x) {
  int i = __float_as_int(x);
  return __int_as_float(__builtin_amdgcn_update_dpp(i, i, CTRL, 0xF, 0xF, false));
}

// R5-proven convention-proof butterfly element (lower: sum, upper: left-right).
template<int HL>
__device__ __forceinline__ float bfly1(float self, bool up) {
#if __has_builtin(__builtin_amdgcn_permlane32_swap)
  if constexpr (HL == 32) {
    i32x2 rr = __builtin_amdgcn_permlane32_swap(__float_as_int(self), __float_as_int(self), false, false);
    float s = __int_as_float(rr.x) + __int_as_float(rr.y);
    return up ? (s - 2.0f * self) : s;
  }
#endif
#if __has_builtin(__builtin_amdgcn_permlane16_swap)
  if constexpr (HL == 16) {
    i32x2 rr = __builtin_amdgcn_permlane16_swap(__float_as_int(self), __float_as_int(self), false, false);
    float s = __int_as_float(rr.x) + __int_as_float(rr.y);
    return up ? (s - 2.0f * self) : s;
  }
#endif
  float pv;
  if constexpr (HL == 8)      pv = dppf<0x128>(self);  // row_ror:8 == lane^8
  else if constexpr (HL == 2) pv = dppf<0x4E>(self);   // quad_perm == lane^2
  else if constexpr (HL == 1) pv = dppf<0xB1>(self);   // quad_perm == lane^1
  else                        pv = shflx(self, HL);    // HL==4 (+ fallbacks)
  float s = self + pv;
  float d = up ? (pv - self) : (self - pv);
  return up ? d : s;
}

// In-lane stage for h <= 16 on the 32-elem chunk.
template<int H>
__device__ __forceinline__ void stage_inlane(float v[32]) {
#pragma unroll
  for (int o = 0; o < 32; o += 2 * H) {
    float dt[H];
#pragma unroll
    for (int i = 0; i < H; ++i) {
      float a = v[o + i], b = v[o + H + i];
      dt[i] = a - b;
      v[o + i] = a + b;
    }
#pragma unroll
    for (int i = H - 1; i >= 1; --i) v[o + H + i] = dt[i] + dt[i - 1];
    v[o + H] = dt[0] + dt[H - 1];
  }
}

// Cross-lane stage, h = HL*32 (HL = 32..1), chunk = 32 elems/lane.
template<int HL>
__device__ __forceinline__ void stage_xlane(float v[32], int lane) {
  const bool up = (lane & HL) != 0;
  const int srcl = ((lane & (HL - 1)) == 0) ? (lane | (HL - 1)) : (lane - 1);
#pragma unroll
  for (int r = 0; r < 32; ++r) v[r] = bfly1<HL>(v[r], up);
  float dw = shfls(v[31], srcl);   // neighbor diff[31] for the r==0 roll
#pragma unroll
  for (int r = 31; r >= 1; --r) {
    float d2 = v[r] + v[r - 1];
    v[r] = up ? d2 : v[r];
  }
  float d2 = v[0] + dw;
  v[0] = up ? d2 : v[0];
}

// h=2048 stage (R6-proven): partner in the other wave of the pair; exchange in
// 2 chunks of 16 via b32 conflict-free scratch (j*64 + lane).
__device__ __forceinline__ void stage_pair(float v[32], int lane, int p, float* scr) {
#pragma unroll
  for (int c = 0; c < 2; ++c) {
    float* dst = scr + p * 1024 + lane;
#pragma unroll
    for (int j = 0; j < 16; ++j) dst[j * 64] = v[16 * c + j];
    __syncthreads();
    const float* sp = scr + (p ^ 1) * 1024 + lane;
    float pv[16];
#pragma unroll
    for (int j = 0; j < 16; ++j) pv[j] = sp[j * 64];
    if (p) {
#pragma unroll
      for (int j = 0; j < 16; ++j) v[16 * c + j] = pv[j] - v[16 * c + j];
    } else {
#pragma unroll
      for (int j = 0; j < 16; ++j) v[16 * c + j] = v[16 * c + j] + pv[j];
    }
    __syncthreads();   // chunk c read complete before chunk c+1 overwrites
  }
  if (p) {             // roll over the 2048-block (wave-uniform branch)
    const int srcl = (lane == 0) ? 63 : lane - 1;
    float dw = shfls(v[31], srcl);
#pragma unroll
    for (int r = 31; r >= 1; --r) v[r] = v[r] + v[r - 1];
    v[0] = v[0] + dw;
  }
}

__device__ __forceinline__ void fhh32(float v[32], int lane, int p, float* scr) {
  stage_pair(v, lane, p, scr);  // h=2048
  stage_xlane<32>(v, lane);     // h=1024
  stage_xlane<16>(v, lane);     // h=512
  stage_xlane<8>(v, lane);      // h=256
  stage_xlane<4>(v, lane);      // h=128
  stage_xlane<2>(v, lane);      // h=64
  stage_xlane<1>(v, lane);      // h=32
  stage_inlane<16>(v);          // h=16
  stage_inlane<8>(v);
  stage_inlane<4>(v);
  stage_inlane<2>(v);
  stage_inlane<1>(v);           // h=1
}

__global__ __launch_bounds__(TPB, 4) void aleph_fused(
    const float* __restrict__ x, const float* __restrict__ sw,
    const float* __restrict__ V, const int* __restrict__ I,
    float* __restrict__ out) {
  __shared__ float scratch[ROWS * 2048];         // 64 KB pair-exchange
  __shared__ unsigned short img[DIM * ROWS];     // 64 KB bf16 image (d, 8 rows)
  char* lb = (char*)img;
  const int t = threadIdx.x;
  const int w = t >> 6;
  const int lane = t & 63;
  const int rb = w >> 1;        // row within block (0..7)
  const int p = w & 1;          // half of the row
  const size_t row = (size_t)blockIdx.x * ROWS + rb;
  float* scr = scratch + rb * 2048;
  const int dbase = p * 2048 + lane * 32;   // first d of this lane's chunk

  float v[32];
  {
    const float4* xp = (const float4*)(x + row * DIM + dbase);
#pragma unroll
    for (int i = 0; i < 8; ++i) {
      float4 f = xp[i];
      v[4 * i] = f.x; v[4 * i + 1] = f.y; v[4 * i + 2] = f.z; v[4 * i + 3] = f.w;
    }
  }
  fhh32(v, lane, p, scr);   // wave pair = transform of its row

#pragma unroll
  for (int r = 0; r < 32; ++r)
    *(unsigned short*)(lb + swz8(dbase + r) + 2 * rb) = bfp(v[r]);
  __syncthreads();

  // Gather: thread t owns d = ii*1024 + t; one ds_read_b128 yields all 8 rows.
  float preg[DPT][ROWS];
#pragma unroll
  for (int ii = 0; ii < DPT; ++ii) {
    const int d = ii * TPB + t;
    const float swd = sw[d];
    uint4 q = *(const uint4*)(lb + swz8(d));
    float a0 = blo(q.x) * swd, a1 = bhi(q.x) * swd;
    float a2 = blo(q.y) * swd, a3 = bhi(q.y) * swd;
    float a4 = blo(q.z) * swd, a5 = bhi(q.z) * swd;
    float a6 = blo(q.w) * swd, a7 = bhi(q.w) * swd;
    const int4*   ip = (const int4*)(I + d * KNZ);
    const float4* vp = (const float4*)(V + d * KNZ);
#pragma unroll 5
    for (int g = 0; g < KNZ / 4; ++g) {
      int4 i4 = ip[g];
      float4 f4 = vp[g];
      {
        uint4 qa = *(const uint4*)(lb + swz8(i4.x));
        a0 += blo(qa.x) * f4.x; a1 += bhi(qa.x) * f4.x;
        a2 += blo(qa.y) * f4.x; a3 += bhi(qa.y) * f4.x;
        a4 += blo(qa.z) * f4.x; a5 += bhi(qa.z) * f4.x;
        a6 += blo(qa.w) * f4.x; a7 += bhi(qa.w) * f4.x;
      }
      {
        uint4 qa = *(const uint4*)(lb + swz8(i4.y));
        a0 += blo(qa.x) * f4.y; a1 += bhi(qa.x) * f4.y;
        a2 += blo(qa.y) * f4.y; a3 += bhi(qa.y) * f4.y;
        a4 += blo(qa.z) * f4.y; a5 += bhi(qa.z) * f4.y;
        a6 += blo(qa.w) * f4.y; a7 += bhi(qa.w) * f4.y;
      }
      {
        uint4 qa = *(const uint4*)(lb + swz8(i4.z));
        a0 += blo(qa.x) * f4.z; a1 += bhi(qa.x) * f4.z;
        a2 += blo(qa.y) * f4.z; a3 += bhi(qa.y) * f4.z;
        a4 += blo(qa.z) * f4.z; a5 += bhi(qa.z) * f4.z;
        a6 += blo(qa.w) * f4.z; a7 += bhi(qa.w) * f4.z;
      }
      {
        uint4 qa = *(const uint4*)(lb + swz8(i4.w));
        a0 += blo(qa.x) * f4.w; a1 += bhi(qa.x) * f4.w;
        a2 += blo(qa.y) * f4.w; a3 += bhi(qa.y) * f4.w;
        a4 += blo(qa.z) * f4.w; a5 += bhi(qa.z) * f4.w;
        a6 += blo(qa.w) * f4.w; a7 += bhi(qa.w) * f4.w;
      }
    }
    preg[ii][0] = a0; preg[ii][1] = a1; preg[ii][2] = a2; preg[ii][3] = a3;
    preg[ii][4] = a4; preg[ii][5] = a5; preg[ii][6] = a6; preg[ii][7] = a7;
  }
  __syncthreads();   // all gathers done before in-place overwrite

#pragma unroll
  for (int ii = 0; ii < DPT; ++ii) {
    const int d = ii * TPB + t;
    uint4 pk;
    pk.x = (unsigned)bfp(preg[ii][0]) | ((unsigned)bfp(preg[ii][1]) << 16);
    pk.y = (unsigned)bfp(preg[ii][2]) | ((unsigned)bfp(preg[ii][3]) << 16);
    pk.z = (unsigned)bfp(preg[ii][4]) | ((unsigned)bfp(preg[ii][5]) << 16);
    pk.w = (unsigned)bfp(preg[ii][6]) | ((unsigned)bfp(preg[ii][7]) << 16);
    *(uint4*)(lb + swz8(d)) = pk;
  }
  __syncthreads();

#pragma unroll
  for (int r = 0; r < 32; ++r)
    v[r] = bfu(*(const unsigned short*)(lb + swz8(dbase + r) + 2 * rb));
  fhh32(v, lane, p, scr);   // img dead after reload; scratch reuse safe

  const float inv = 1.0f / (float)DIM;
  float4* op = (float4*)(out + row * DIM + dbase);
#pragma unroll
  for (int i = 0; i < 8; ++i) {
    float4 f;
    f.x = v[4 * i] * inv;     f.y = v[4 * i + 1] * inv;
    f.z = v[4 * i + 2] * inv; f.w = v[4 * i + 3] * inv;
    op[i] = f;
  }
}

extern "C" void kernel_launch(void* const* d_in, const int* in_sizes, int n_in,
                              void* d_out, int out_size, void* d_ws, size_t ws_size,
                              hipStream_t stream) {
  const float* x  = (const float*)d_in[0];   // (2048, 4096) f32
  const float* sw = (const float*)d_in[1];   // (4096,) f32
  const float* V  = (const float*)d_in[2];   // (4096, 40) f32
  const int*   I  = (const int*)d_in[3];     // (4096, 40) i32
  float* out = (float*)d_out;                // (2048, 4096) f32

  dim3 grid(BATCH / ROWS), block(TPB);       // 256 blocks, 16 waves each
  hipLaunchKernelGGL(aleph_fused, grid, block, 0, stream, x, sw, V, I, out);
}

// Round 8
// 78.643 us; speedup vs baseline: 1.3994x; 1.0097x over previous
//
#include <hip/hip_runtime.h>

#define DIM   4096
#define BATCH 2048
#define KNZ   40
#define ROWS  8
#define TPB   512
#define DPT   (DIM / TPB)   // 8 d's per thread

typedef int i32x2 __attribute__((ext_vector_type(2)));

__device__ __forceinline__ float shflx(float v, int m) { return __shfl_xor(v, m, 64); }
__device__ __forceinline__ float shfls(float v, int s) { return __shfl(v, s, 64); }

// byte offset of the 16B row-group (8 bf16 rows) for dim index d. R4-proven.
__device__ __forceinline__ int swz8(int d) { return (d << 4) ^ ((d >> 2) & 0x1f0); }

__device__ __forceinline__ unsigned short bfp(float f) {   // f32 -> bf16 RNE
  unsigned u = __float_as_uint(f);
  u += 0x7fffu + ((u >> 16) & 1u);
  return (unsigned short)(u >> 16);
}
__device__ __forceinline__ float bfu(unsigned short h) { return __uint_as_float(((unsigned)h) << 16); }
__device__ __forceinline__ float blo(unsigned u) { return __uint_as_float(u << 16); }
__device__ __forceinline__ float bhic(unsigned u) { return __uint_as_float(u & 0xffff0000u); } // clean
__device__ __forceinline__ float bhir(unsigned u) { return __uint_as_float(u); }               // raw (garbage low bits, 2^-8 rel)

template<int CTRL>
__device__ __forceinline__ float dppf(float x) {
  int i = __float_as_int(x);
  return __int_as_float(__builtin_amdgcn_update_dpp(i, i, CTRL, 0xF, 0xF, false));
}

// In-lane stage for h <= 32: blocks of 2H inside each lane's 64-elem chunk.
template<int H>
__device__ __forceinline__ void stage_inlane(float v[64]) {
#pragma unroll
  for (int o = 0; o < 64; o += 2 * H) {
    float dt[H];
#pragma unroll
    for (int i = 0; i < H; ++i) {
      float a = v[o + i], b = v[o + H + i];
      dt[i] = a - b;
      v[o + i] = a + b;
    }
#pragma unroll
    for (int i = H - 1; i >= 1; --i) v[o + H + i] = dt[i] + dt[i - 1];
    v[o + H] = dt[0] + dt[H - 1];
  }
}

// Cross-lane stage for h >= 64 (HL = h/64). Select-free: per-lane constants
// sgn/cswap/rm turn butterfly + roll into pure fma (no cndmask).
//   down lane: pv + self       = fma(self, +1, pv)   (or s2 + 0*self)
//   up   lane: pv - self       = fma(self, -1, pv)   (or s2 - 2*self)
//   roll     : v[r] += rm * v_old[r-1], rm = up ? 1 : 0
template<int HL>
__device__ __forceinline__ void stage_xlane(float v[64], int lane) {
  const bool up = (lane & HL) != 0;
  const float sgn   = up ? -1.0f : 1.0f;
  const float cswap = up ? -2.0f : 0.0f;
  const float rm    = up ? 1.0f : 0.0f;
  const int srcl = ((lane & (HL - 1)) == 0) ? (lane | (HL - 1)) : (lane - 1);
#pragma unroll
  for (int r = 0; r < 64; ++r) {
    float self = v[r];
    bool done = false;
#if __has_builtin(__builtin_amdgcn_permlane32_swap)
    if constexpr (HL == 32) {
      i32x2 rr = __builtin_amdgcn_permlane32_swap(__float_as_int(self), __float_as_int(self), false, false);
      float s2 = __int_as_float(rr.x) + __int_as_float(rr.y);   // self + partner (order-proof)
      v[r] = fmaf(self, cswap, s2);
      done = true;
    }
#endif
#if __has_builtin(__builtin_amdgcn_permlane16_swap)
    if constexpr (HL == 16) {
      i32x2 rr = __builtin_amdgcn_permlane16_swap(__float_as_int(self), __float_as_int(self), false, false);
      float s2 = __int_as_float(rr.x) + __int_as_float(rr.y);
      v[r] = fmaf(self, cswap, s2);
      done = true;
    }
#endif
    if (!done) {
      float pv;
      if constexpr (HL == 8)      pv = dppf<0x128>(self);  // row_ror:8 == lane^8
      else if constexpr (HL == 2) pv = dppf<0x4E>(self);   // quad_perm == lane^2
      else if constexpr (HL == 1) pv = dppf<0xB1>(self);   // quad_perm == lane^1
      else                        pv = shflx(self, HL);    // HL==4 (+ fallbacks)
      v[r] = fmaf(self, sgn, pv);
    }
  }
  float dw = shfls(v[63], srcl);   // partner diff[63] for the r==0 roll
#pragma unroll
  for (int r = 63; r >= 1; --r) v[r] = fmaf(v[r - 1], rm, v[r]);
  v[0] = fmaf(dw, rm, v[0]);
}

__device__ __forceinline__ void fhh_regs(float v[64], int lane) {
  stage_xlane<32>(v, lane);
  stage_xlane<16>(v, lane);
  stage_xlane<8>(v, lane);
  stage_xlane<4>(v, lane);
  stage_xlane<2>(v, lane);
  stage_xlane<1>(v, lane);
  stage_inlane<32>(v);
  stage_inlane<16>(v);
  stage_inlane<8>(v);
  stage_inlane<4>(v);
  stage_inlane<2>(v);
  stage_inlane<1>(v);
}

// Prep: pre-swizzle engram indices to LDS byte offsets (run once per launch).
__global__ void prep_idx(const int* __restrict__ I, int* __restrict__ PS, int n) {
  int i = blockIdx.x * 256 + threadIdx.x;
  if (i < n) PS[i] = swz8(I[i]);
}

template<bool PRE>
__global__ __launch_bounds__(TPB, 2) void aleph_fused(
    const float* __restrict__ x, const float* __restrict__ sw,
    const float* __restrict__ V, const int* __restrict__ IDX,
    float* __restrict__ out) {
  // interleaved bf16: (d, row) at byte swz8(d) + 2*row.  64 KB.
  __shared__ unsigned short img[DIM * ROWS];
  char* lb = (char*)img;
  const int t = threadIdx.x;
  const int w = t >> 6;          // wave id = row within block (0..7)
  const int lane = t & 63;
  const size_t row = (size_t)blockIdx.x * ROWS + w;

  float v[64];
  {
    const float4* xp = (const float4*)(x + row * DIM + (size_t)lane * 64);
#pragma unroll
    for (int i = 0; i < 16; ++i) {
      float4 f = xp[i];
      v[4 * i] = f.x; v[4 * i + 1] = f.y; v[4 * i + 2] = f.z; v[4 * i + 3] = f.w;
    }
  }
  fhh_regs(v, lane);   // wave chunk: lane holds d = 64*lane + r

#pragma unroll
  for (int r = 0; r < 64; ++r)
    *(unsigned short*)(lb + swz8(64 * lane + r) + 2 * w) = bfp(v[r]);
  __syncthreads();

  // Gather: thread t owns d = ii*512 + t; one ds_read_b128 yields all 8 rows.
  float preg[DPT][ROWS];
#pragma unroll
  for (int ii = 0; ii < DPT; ++ii) {
    const int d = ii * TPB + t;
    const float swd = sw[d];
    uint4 q = *(const uint4*)(lb + swz8(d));
    float a0 = blo(q.x) * swd, a1 = bhic(q.x) * swd;   // self: clean unpack
    float a2 = blo(q.y) * swd, a3 = bhic(q.y) * swd;
    float a4 = blo(q.z) * swd, a5 = bhic(q.z) * swd;
    float a6 = blo(q.w) * swd, a7 = bhic(q.w) * swd;
    const int4*   ip = (const int4*)(IDX + d * KNZ);   // PRE: byte offsets; else raw indices
    const float4* vp = (const float4*)(V + d * KNZ);
#pragma unroll 5
    for (int g = 0; g < KNZ / 4; ++g) {
      int4 i4 = ip[g];
      float4 f4 = vp[g];
      int o0, o1, o2, o3;
      if constexpr (PRE) { o0 = i4.x; o1 = i4.y; o2 = i4.z; o3 = i4.w; }
      else { o0 = swz8(i4.x); o1 = swz8(i4.y); o2 = swz8(i4.z); o3 = swz8(i4.w); }
      {
        uint4 qa = *(const uint4*)(lb + o0);
        a0 += blo(qa.x) * f4.x; a1 += bhir(qa.x) * f4.x;
        a2 += blo(qa.y) * f4.x; a3 += bhir(qa.y) * f4.x;
        a4 += blo(qa.z) * f4.x; a5 += bhir(qa.z) * f4.x;
        a6 += blo(qa.w) * f4.x; a7 += bhir(qa.w) * f4.x;
      }
      {
        uint4 qa = *(const uint4*)(lb + o1);
        a0 += blo(qa.x) * f4.y; a1 += bhir(qa.x) * f4.y;
        a2 += blo(qa.y) * f4.y; a3 += bhir(qa.y) * f4.y;
        a4 += blo(qa.z) * f4.y; a5 += bhir(qa.z) * f4.y;
        a6 += blo(qa.w) * f4.y; a7 += bhir(qa.w) * f4.y;
      }
      {
        uint4 qa = *(const uint4*)(lb + o2);
        a0 += blo(qa.x) * f4.z; a1 += bhir(qa.x) * f4.z;
        a2 += blo(qa.y) * f4.z; a3 += bhir(qa.y) * f4.z;
        a4 += blo(qa.z) * f4.z; a5 += bhir(qa.z) * f4.z;
        a6 += blo(qa.w) * f4.z; a7 += bhir(qa.w) * f4.z;
      }
      {
        uint4 qa = *(const uint4*)(lb + o3);
        a0 += blo(qa.x) * f4.w; a1 += bhir(qa.x) * f4.w;
        a2 += blo(qa.y) * f4.w; a3 += bhir(qa.y) * f4.w;
        a4 += blo(qa.z) * f4.w; a5 += bhir(qa.z) * f4.w;
        a6 += blo(qa.w) * f4.w; a7 += bhir(qa.w) * f4.w;
      }
    }
    preg[ii][0] = a0; preg[ii][1] = a1; preg[ii][2] = a2; preg[ii][3] = a3;
    preg[ii][4] = a4; preg[ii][5] = a5; preg[ii][6] = a6; preg[ii][7] = a7;
  }
  __syncthreads();   // all gathers done before in-place overwrite

#pragma unroll
  for (int ii = 0; ii < DPT; ++ii) {
    const int d = ii * TPB + t;
    uint4 pk;
    pk.x = (unsigned)bfp(preg[ii][0]) | ((unsigned)bfp(preg[ii][1]) << 16);
    pk.y = (unsigned)bfp(preg[ii][2]) | ((unsigned)bfp(preg[ii][3]) << 16);
    pk.z = (unsigned)bfp(preg[ii][4]) | ((unsigned)bfp(preg[ii][5]) << 16);
    pk.w = (unsigned)bfp(preg[ii][6]) | ((unsigned)bfp(preg[ii][7]) << 16);
    *(uint4*)(lb + swz8(d)) = pk;
  }
  __syncthreads();

#pragma unroll
  for (int r = 0; r < 64; ++r)
    v[r] = bfu(*(const unsigned short*)(lb + swz8(64 * lane + r) + 2 * w));
  fhh_regs(v, lane);

  const float inv = 1.0f / (float)DIM;
  float4* op = (float4*)(out + row * DIM + (size_t)lane * 64);
#pragma unroll
  for (int i = 0; i < 16; ++i) {
    float4 f;
    f.x = v[4 * i] * inv;     f.y = v[4 * i + 1] * inv;
    f.z = v[4 * i + 2] * inv; f.w = v[4 * i + 3] * inv;
    op[i] = f;
  }
}

extern "C" void kernel_launch(void* const* d_in, const int* in_sizes, int n_in,
                              void* d_out, int out_size, void* d_ws, size_t ws_size,
                              hipStream_t stream) {
  const float* x  = (const float*)d_in[0];   // (2048, 4096) f32
  const float* sw = (const float*)d_in[1];   // (4096,) f32
  const float* V  = (const float*)d_in[2];   // (4096, 40) f32
  const int*   I  = (const int*)d_in[3];     // (4096, 40) i32
  float* out = (float*)d_out;                // (2048, 4096) f32

  dim3 grid(BATCH / ROWS), block(TPB);
  const int nidx = DIM * KNZ;                // 163840
  if (ws_size >= (size_t)nidx * sizeof(int)) {
    int* PS = (int*)d_ws;
    hipLaunchKernelGGL(prep_idx, dim3((nidx + 255) / 256), dim3(256), 0, stream, I, PS, nidx);
    hipLaunchKernelGGL(aleph_fused<true>, grid, block, 0, stream, x, sw, V, PS, out);
  } else {
    hipLaunchKernelGGL(aleph_fused<false>, grid, block, 0, stream, x, sw, V, I, out);
  }
}